// Round 4
// baseline (279.603 us; speedup 1.0000x reference)
//
#include <hip/hip_runtime.h>

// Problem constants (from reference)
#define N_NODES 50000
#define N_EDGES (7 * N_NODES)   // 350000
#define BATCH 4
#define DIM 128
#define D4 (DIM / 4)            // 32 float4 chunks per row
#define CAP 32                  // per-node bucket capacity (in-degree ~ Poisson(7))
#define CPAD 16                 // counter padding (64B) to kill cross-XCD false sharing

// ---- workspace layout (ints) ----
#define WS_COUNTS  0                            // N_NODES counters, stride CPAD
#define WS_OVFCNT  (N_NODES * CPAD)             // 1 int, zeroed by the counts memset
#define WS_META    (N_NODES * CPAD + 256)       // N_NODES*CAP packed src|typ<<20 (0xFF = empty)
#define WS_OVF     (WS_META + N_NODES * CAP)    // worst-case overflow (m, dst) pairs
#define WS_TOTAL_INTS (WS_OVF + 2 * N_EDGES)

// ---------------- bucket path ----------------

// One thread per edge: append (src|typ) to dst's bucket; overflow -> list.
__global__ __launch_bounds__(256)
void bucket_scatter_kernel(const int* __restrict__ ei,
                           int* __restrict__ counts,
                           int* __restrict__ ovf_cnt,
                           int* __restrict__ meta,
                           int* __restrict__ ovf) {
    int e = blockIdx.x * 256 + threadIdx.x;
    if (e >= N_EDGES) return;
    int src = ei[e];
    int dst = ei[N_EDGES + e];
    int typ = ei[2 * N_EDGES + e];
    int m = src | (typ << 20);
    int pos = atomicAdd(&counts[dst * CPAD], 1);
    if (pos < CAP) {
        meta[dst * CAP + pos] = m;
    } else {
        int oi = atomicAdd(ovf_cnt, 1);
        ovf[2 * oi]     = m;
        ovf[2 * oi + 1] = dst;
    }
}

// One WAVE per node, all 4 batches. Lane = (p<<5) | d4, p in {0,1};
// thread handles batches p and p+2. Node is wave-uniform, so the per-edge
// meta broadcast is a scalar readlane (no ds_bpermute serial chain), and
// each thread issues 2 independent x gathers per edge (2x MLP).
__global__ __launch_bounds__(256)
void gather_kernel(const float* __restrict__ x,
                   const float* __restrict__ w,
                   const float* __restrict__ bias,
                   const int* __restrict__ meta,
                   float* __restrict__ out) {
    int lane = threadIdx.x & 63;
    int d4   = lane & 31;
    int p    = lane >> 5;                          // 0 or 1
    int n    = blockIdx.x * 4 + (threadIdx.x >> 6); // node = global wave index
    if (n >= N_NODES) return;

    const float4* x4 = reinterpret_cast<const float4*>(x);
    const float4* w4 = reinterpret_cast<const float4*>(w);
    const float4* b4 = reinterpret_cast<const float4*>(bias);

    int mreg = meta[n * CAP + d4];                 // one 128B line per node
    unsigned long long vm = __ballot(mreg != -1);  // slots fill from 0 -> contiguous
    int cnt = __popcll(vm & 0xFFFFFFFFull);

    float4 bv = b4[d4];
    float4 a0 = bv;                                // batch p
    float4 a1 = bv;                                // batch p+2

    for (int k = 0; k < cnt; ++k) {
        int m   = __builtin_amdgcn_readlane(mreg, k);  // SGPR broadcast
        int src = m & 0xFFFFF;
        int typ = m >> 20;
        float4 wv = w4[typ * D4 + d4];
        float4 v0 = x4[(size_t)(p * N_NODES + src) * D4 + d4];
        float4 v1 = x4[(size_t)((p + 2) * N_NODES + src) * D4 + d4];
        a0.x += wv.x * v0.x; a0.y += wv.y * v0.y; a0.z += wv.z * v0.z; a0.w += wv.w * v0.w;
        a1.x += wv.x * v1.x; a1.y += wv.y * v1.y; a1.z += wv.z * v1.z; a1.w += wv.w * v1.w;
    }

    float4* o4 = reinterpret_cast<float4*>(out);
    o4[(size_t)(p * N_NODES + n) * D4 + d4]       = a0;
    o4[(size_t)((p + 2) * N_NODES + n) * D4 + d4] = a1;
}

// Rare overflow edges (deg > CAP): atomic adds, normally zero work.
__global__ __launch_bounds__(256)
void ovf_fix_kernel(const float* __restrict__ x,
                    const float* __restrict__ w,
                    const int* __restrict__ ovf_cnt,
                    const int* __restrict__ ovf,
                    float* __restrict__ out) {
    int total = *ovf_cnt;
    if (total <= 0) return;
    const float4* x4 = reinterpret_cast<const float4*>(x);
    const float4* w4 = reinterpret_cast<const float4*>(w);
    int stride = gridDim.x * blockDim.x;
    for (int t = blockIdx.x * blockDim.x + threadIdx.x; t < total * D4; t += stride) {
        int e  = t >> 5;
        int d4 = t & 31;
        int m   = ovf[2 * e];
        int dst = ovf[2 * e + 1];
        int src = m & 0xFFFFF;
        int typ = m >> 20;
        float4 wv = w4[typ * D4 + d4];
        #pragma unroll
        for (int b = 0; b < BATCH; ++b) {
            float4 xv = x4[(size_t)(b * N_NODES + src) * D4 + d4];
            float* o = out + (size_t)(b * N_NODES + dst) * DIM + d4 * 4;
            atomicAdd(o + 0, wv.x * xv.x);
            atomicAdd(o + 1, wv.y * xv.y);
            atomicAdd(o + 2, wv.z * xv.z);
            atomicAdd(o + 3, wv.w * xv.w);
        }
    }
}

// ---------------- fallback path (if ws too small): round-1 atomics ----------------

__global__ void init_out_kernel(float* __restrict__ out,
                                const float* __restrict__ bias) {
    int i = blockIdx.x * blockDim.x + threadIdx.x;
    const int total = BATCH * N_NODES * D4;
    if (i >= total) return;
    int d4 = i & (D4 - 1);
    reinterpret_cast<float4*>(out)[i] = reinterpret_cast<const float4*>(bias)[d4];
}

__global__ void edge_scatter_kernel(const float* __restrict__ x,
                                    const int* __restrict__ ei,
                                    const float* __restrict__ w,
                                    float* __restrict__ out) {
    int t = blockIdx.x * blockDim.x + threadIdx.x;
    const int total = N_EDGES * D4;
    if (t >= total) return;
    int e  = t >> 5;
    int d4 = t & 31;
    int src = ei[e];
    int dst = ei[N_EDGES + e];
    int typ = ei[2 * N_EDGES + e];
    const float4* x4 = reinterpret_cast<const float4*>(x);
    float4 wv = reinterpret_cast<const float4*>(w)[typ * D4 + d4];
    #pragma unroll
    for (int b = 0; b < BATCH; ++b) {
        float4 xv = x4[(size_t)(b * N_NODES + src) * D4 + d4];
        float* o = out + (size_t)(b * N_NODES + dst) * DIM + d4 * 4;
        atomicAdd(o + 0, xv.x * wv.x);
        atomicAdd(o + 1, xv.y * wv.y);
        atomicAdd(o + 2, xv.z * wv.z);
        atomicAdd(o + 3, xv.w * wv.w);
    }
}

extern "C" void kernel_launch(void* const* d_in, const int* in_sizes, int n_in,
                              void* d_out, int out_size, void* d_ws, size_t ws_size,
                              hipStream_t stream) {
    const float* x    = (const float*)d_in[0];   // (4, 50000, 128) f32
    const int*   ei   = (const int*)d_in[1];     // (3, 350000) i32
    const float* w    = (const float*)d_in[2];   // (1, 7, 128) f32
    const float* bias = (const float*)d_in[3];   // (1, 1, 128) f32
    float* out = (float*)d_out;                  // (4, 50000, 128) f32

    if (ws_size >= (size_t)WS_TOTAL_INTS * sizeof(int)) {
        int* ws      = (int*)d_ws;
        int* counts  = ws + WS_COUNTS;
        int* ovf_cnt = ws + WS_OVFCNT;
        int* meta    = ws + WS_META;
        int* ovf     = ws + WS_OVF;

        // zero padded counters + overflow counter; fill meta with sentinel 0xFF
        hipMemsetAsync(counts, 0, (size_t)(N_NODES * CPAD + 1) * sizeof(int), stream);
        hipMemsetAsync(meta, 0xFF, (size_t)(N_NODES * CAP) * sizeof(int), stream);

        bucket_scatter_kernel<<<(N_EDGES + 255) / 256, 256, 0, stream>>>(
            ei, counts, ovf_cnt, meta, ovf);

        // one wave per node: 4 waves (nodes) per 256-thread block
        gather_kernel<<<(N_NODES + 3) / 4, 256, 0, stream>>>(
            x, w, bias, meta, out);

        ovf_fix_kernel<<<64, 256, 0, stream>>>(x, w, ovf_cnt, ovf, out);
    } else {
        // fallback: atomic scatter (correct for any ws_size)
        init_out_kernel<<<(BATCH * N_NODES * D4 + 255) / 256, 256, 0, stream>>>(out, bias);
        edge_scatter_kernel<<<(N_EDGES * D4 + 255) / 256, 256, 0, stream>>>(x, ei, w, out);
    }
}